// Round 3
// baseline (155.858 us; speedup 1.0000x reference)
//
#include <hip/hip_runtime.h>
#include <hip/hip_cooperative_groups.h>
#include <math.h>

namespace cg = cooperative_groups;

// BondOrderConv: out[e] = sigmoid( nf[src[e]]·W_src + b_src
//                                + nf[dst[e]]·W_dst + b_dst
//                                + ef[e]·W_edge + b_edge )
// F = 256 f32. Memory-bound: ~342 MB total stream -> floor ~54 us @ 6.3 TB/s.
//
// Layout: 16 lanes per row, 4 rows per wave-iteration (4-step butterfly,
// one swizzle reduces 4 rows at once, 4 indep 16B loads in flight per lane).
//
// Fused single cooperative kernel: phase 1 (node gates, 10.2 MB) ->
// grid.sync() -> phase 2 (edge stream, 329 MB). Removes the inter-kernel
// serialization bubble. Fallback: two plain kernels (round-2 known-good).

#define FDIM 256
#define F4   (FDIM / 4)   // 64 float4 per row

__device__ __forceinline__ float dot4(float4 a, float4 b) {
    return a.x * b.x + a.y * b.y + a.z * b.z + a.w * b.w;
}

__device__ __forceinline__ void node_phase(const float* __restrict__ nf,
                                           const float* __restrict__ W_src,
                                           const float* __restrict__ W_dst,
                                           const float* __restrict__ b_src,
                                           const float* __restrict__ b_dst,
                                           float* __restrict__ e_src,
                                           float* __restrict__ e_dst,
                                           int n_nodes, int wave, int nwaves,
                                           int sub, int i) {
    const float4* Ws4 = reinterpret_cast<const float4*>(W_src);
    const float4* Wd4 = reinterpret_cast<const float4*>(W_dst);
    const float4 ws0 = Ws4[i], ws1 = Ws4[i + 16], ws2 = Ws4[i + 32], ws3 = Ws4[i + 48];
    const float4 wd0 = Wd4[i], wd1 = Wd4[i + 16], wd2 = Wd4[i + 32], wd3 = Wd4[i + 48];
    const float bs = b_src[0];
    const float bd = b_dst[0];

    const int ngroups = (n_nodes + 3) >> 2;
    for (int g = wave; g < ngroups; g += nwaves) {
        const int n = g * 4 + sub;
        if (n >= n_nodes) continue;
        const float4* row = reinterpret_cast<const float4*>(nf) + (size_t)n * F4;
        const float4 x0 = row[i], x1 = row[i + 16], x2 = row[i + 32], x3 = row[i + 48];
        float ss = dot4(x0, ws0) + dot4(x1, ws1) + dot4(x2, ws2) + dot4(x3, ws3);
        float sd = dot4(x0, wd0) + dot4(x1, wd1) + dot4(x2, wd2) + dot4(x3, wd3);
        #pragma unroll
        for (int off = 1; off < 16; off <<= 1) {
            ss += __shfl_xor(ss, off, 64);
            sd += __shfl_xor(sd, off, 64);
        }
        if (i == 0) {
            e_src[n] = ss + bs;
            e_dst[n] = sd + bd;
        }
    }
}

__device__ __forceinline__ void edge_phase(const float* __restrict__ ef,
                                           const int* __restrict__ src,
                                           const int* __restrict__ dst,
                                           const float* __restrict__ W_edge,
                                           const float* __restrict__ b_edge,
                                           const float* __restrict__ e_src,
                                           const float* __restrict__ e_dst,
                                           float* __restrict__ out,
                                           int n_edges, int wave, int nwaves,
                                           int sub, int i) {
    const float4* We4 = reinterpret_cast<const float4*>(W_edge);
    const float4 w0 = We4[i], w1 = We4[i + 16], w2 = We4[i + 32], w3 = We4[i + 48];
    const float be = b_edge[0];

    const int ngroups = (n_edges + 3) >> 2;
    for (int g = wave; g < ngroups; g += nwaves) {
        const int e = g * 4 + sub;
        if (e >= n_edges) continue;
        const float4* row = reinterpret_cast<const float4*>(ef) + (size_t)e * F4;
        const float4 x0 = row[i], x1 = row[i + 16], x2 = row[i + 32], x3 = row[i + 48];
        float s = dot4(x0, w0) + dot4(x1, w1) + dot4(x2, w2) + dot4(x3, w3);
        #pragma unroll
        for (int off = 1; off < 16; off <<= 1) {
            s += __shfl_xor(s, off, 64);
        }
        if (i == 0) {
            const float m = s + be + e_src[src[e]] + e_dst[dst[e]];
            out[e] = 1.0f / (1.0f + expf(-m));
        }
    }
}

// ---- Fused cooperative kernel ----
__global__ void __launch_bounds__(256, 8)
fused_kernel(const float* __restrict__ nf, const float* __restrict__ ef,
             const int* __restrict__ src, const int* __restrict__ dst,
             const float* __restrict__ W_src, const float* __restrict__ b_src,
             const float* __restrict__ W_dst, const float* __restrict__ b_dst,
             const float* __restrict__ W_edge, const float* __restrict__ b_edge,
             float* __restrict__ e_src, float* __restrict__ e_dst,
             float* __restrict__ out, int n_nodes, int n_edges) {
    const int lane   = threadIdx.x & 63;
    const int sub    = lane >> 4;
    const int i      = lane & 15;
    const int wave   = (blockIdx.x * blockDim.x + threadIdx.x) >> 6;
    const int nwaves = (gridDim.x * blockDim.x) >> 6;

    node_phase(nf, W_src, W_dst, b_src, b_dst, e_src, e_dst,
               n_nodes, wave, nwaves, sub, i);
    cg::this_grid().sync();
    edge_phase(ef, src, dst, W_edge, b_edge, e_src, e_dst, out,
               n_edges, wave, nwaves, sub, i);
}

// ---- Fallback standalone kernels (round-2 known-good path) ----
__global__ void node_gates_kernel(const float* __restrict__ nf,
                                  const float* __restrict__ W_src,
                                  const float* __restrict__ W_dst,
                                  const float* __restrict__ b_src,
                                  const float* __restrict__ b_dst,
                                  float* __restrict__ e_src,
                                  float* __restrict__ e_dst,
                                  int n_nodes) {
    const int lane   = threadIdx.x & 63;
    const int wave   = (blockIdx.x * blockDim.x + threadIdx.x) >> 6;
    const int nwaves = (gridDim.x * blockDim.x) >> 6;
    node_phase(nf, W_src, W_dst, b_src, b_dst, e_src, e_dst,
               n_nodes, wave, nwaves, lane >> 4, lane & 15);
}

__global__ void edge_gate_kernel(const float* __restrict__ ef,
                                 const int* __restrict__ src,
                                 const int* __restrict__ dst,
                                 const float* __restrict__ W_edge,
                                 const float* __restrict__ b_edge,
                                 const float* __restrict__ e_src,
                                 const float* __restrict__ e_dst,
                                 float* __restrict__ out,
                                 int n_edges) {
    const int lane   = threadIdx.x & 63;
    const int wave   = (blockIdx.x * blockDim.x + threadIdx.x) >> 6;
    const int nwaves = (gridDim.x * blockDim.x) >> 6;
    edge_phase(ef, src, dst, W_edge, b_edge, e_src, e_dst, out,
               n_edges, wave, nwaves, lane >> 4, lane & 15);
}

extern "C" void kernel_launch(void* const* d_in, const int* in_sizes, int n_in,
                              void* d_out, int out_size, void* d_ws, size_t ws_size,
                              hipStream_t stream) {
    const float* node_feats = (const float*)d_in[0];
    const float* edge_feats = (const float*)d_in[1];
    const int*   src        = (const int*)d_in[2];
    const int*   dst        = (const int*)d_in[3];
    const float* W_src      = (const float*)d_in[4];
    const float* b_src      = (const float*)d_in[5];
    const float* W_dst      = (const float*)d_in[6];
    const float* b_dst      = (const float*)d_in[7];
    const float* W_edge     = (const float*)d_in[8];
    const float* b_edge     = (const float*)d_in[9];

    const int n_nodes = in_sizes[0] / FDIM;
    const int n_edges = in_sizes[2];

    float* e_src = (float*)d_ws;
    float* e_dst = e_src + n_nodes;
    float* outp  = (float*)d_out;

    // Try cooperative fused launch, sized to guaranteed co-residency.
    int occ = 0;
    hipError_t err = hipOccupancyMaxActiveBlocksPerMultiprocessor(
        &occ, fused_kernel, 256, 0);
    if (err == hipSuccess && occ > 0) {
        int blocks = occ * 256;              // 256 CUs on MI355X
        if (blocks > 2048) blocks = 2048;
        void* args[] = {
            (void*)&node_feats, (void*)&edge_feats,
            (void*)&src, (void*)&dst,
            (void*)&W_src, (void*)&b_src,
            (void*)&W_dst, (void*)&b_dst,
            (void*)&W_edge, (void*)&b_edge,
            (void*)&e_src, (void*)&e_dst,
            (void*)&outp, (void*)&n_nodes, (void*)&n_edges,
        };
        err = hipLaunchCooperativeKernel((void*)fused_kernel,
                                         dim3(blocks), dim3(256),
                                         args, 0, stream);
        if (err == hipSuccess) return;
    }

    // Fallback: two-kernel path (known-good, ~62.8 us).
    {
        int ngroups = (n_nodes + 3) / 4;
        int blocks = (ngroups + 3) / 4;
        if (blocks > 2048) blocks = 2048;
        node_gates_kernel<<<blocks, 256, 0, stream>>>(
            node_feats, W_src, W_dst, b_src, b_dst, e_src, e_dst, n_nodes);
    }
    {
        edge_gate_kernel<<<2048, 256, 0, stream>>>(
            edge_feats, src, dst, W_edge, b_edge, e_src, e_dst,
            outp, n_edges);
    }
}

// Round 4
// 67.523 us; speedup vs baseline: 2.3082x; 2.3082x over previous
//
#include <hip/hip_runtime.h>
#include <math.h>

// BondOrderConv: out[e] = sigmoid( nf[src[e]]·W_src + b_src
//                                + nf[dst[e]]·W_dst + b_dst
//                                + ef[e]·W_edge + b_edge )
// F = 256 f32. Memory-bound: ~342 MB total stream -> floor ~54 us @ 6.3 TB/s.
//
// Round-3 lesson: cooperative fused launch tanks streaming BW (726 GB/s vs
// 5.9 TB/s) — keep the plain two-kernel structure.
//
// Layout: 8 lanes per row, 8 rows per wave-iteration.
//   lane = 8*sub + i;  lane covers float4 columns i, i+8, ..., i+56
//   -> 8 independent 16B loads in flight per lane, 3-step width-8 butterfly,
//      one swizzle reduces 8 rows at once. E and N both divide by 8 (no tail).

#define FDIM 256
#define F4   (FDIM / 4)   // 64 float4 per row

__device__ __forceinline__ float dot4(float4 a, float4 b) {
    return a.x * b.x + a.y * b.y + a.z * b.z + a.w * b.w;
}

// Kernel 1: per-node gate scalars (two dots per node).
__global__ void node_gates_kernel(const float* __restrict__ nf,
                                  const float* __restrict__ W_src,
                                  const float* __restrict__ W_dst,
                                  const float* __restrict__ b_src,
                                  const float* __restrict__ b_dst,
                                  float* __restrict__ e_src,
                                  float* __restrict__ e_dst,
                                  int n_nodes) {
    const int lane   = threadIdx.x & 63;
    const int sub    = lane >> 3;        // which of 8 nodes
    const int i      = lane & 7;         // column lane within node
    const int wave   = (blockIdx.x * blockDim.x + threadIdx.x) >> 6;
    const int nwaves = (gridDim.x * blockDim.x) >> 6;

    const float4* Ws4 = reinterpret_cast<const float4*>(W_src);
    const float4* Wd4 = reinterpret_cast<const float4*>(W_dst);
    float4 ws[8], wd[8];
    #pragma unroll
    for (int k = 0; k < 8; ++k) { ws[k] = Ws4[i + 8 * k]; wd[k] = Wd4[i + 8 * k]; }
    const float bs = b_src[0];
    const float bd = b_dst[0];

    const int ngroups = (n_nodes + 7) >> 3;
    for (int g = wave; g < ngroups; g += nwaves) {
        const int n = g * 8 + sub;
        if (n >= n_nodes) continue;
        const float4* row = reinterpret_cast<const float4*>(nf) + (size_t)n * F4;
        float4 x[8];
        #pragma unroll
        for (int k = 0; k < 8; ++k) x[k] = row[i + 8 * k];
        float ss = 0.f, sd = 0.f;
        #pragma unroll
        for (int k = 0; k < 8; ++k) { ss += dot4(x[k], ws[k]); sd += dot4(x[k], wd[k]); }
        #pragma unroll
        for (int off = 1; off < 8; off <<= 1) {
            ss += __shfl_xor(ss, off, 64);
            sd += __shfl_xor(sd, off, 64);
        }
        if (i == 0) {
            e_src[n] = ss + bs;
            e_dst[n] = sd + bd;
        }
    }
}

// Kernel 2: per-edge gate + gather + sigmoid (329 MB stream — the hot kernel).
__global__ void edge_gate_kernel(const float* __restrict__ ef,
                                 const int* __restrict__ src,
                                 const int* __restrict__ dst,
                                 const float* __restrict__ W_edge,
                                 const float* __restrict__ b_edge,
                                 const float* __restrict__ e_src,
                                 const float* __restrict__ e_dst,
                                 float* __restrict__ out,
                                 int n_edges) {
    const int lane   = threadIdx.x & 63;
    const int sub    = lane >> 3;        // which of 8 edges
    const int i      = lane & 7;         // column lane within edge
    const int wave   = (blockIdx.x * blockDim.x + threadIdx.x) >> 6;
    const int nwaves = (gridDim.x * blockDim.x) >> 6;

    const float4* We4 = reinterpret_cast<const float4*>(W_edge);
    float4 w[8];
    #pragma unroll
    for (int k = 0; k < 8; ++k) w[k] = We4[i + 8 * k];
    const float be = b_edge[0];

    const int ngroups = (n_edges + 7) >> 3;
    for (int g = wave; g < ngroups; g += nwaves) {
        const int e = g * 8 + sub;
        if (e >= n_edges) continue;
        const float4* row = reinterpret_cast<const float4*>(ef) + (size_t)e * F4;
        float4 x[8];
        #pragma unroll
        for (int k = 0; k < 8; ++k) x[k] = row[i + 8 * k];
        float s = 0.f;
        #pragma unroll
        for (int k = 0; k < 8; ++k) s += dot4(x[k], w[k]);
        #pragma unroll
        for (int off = 1; off < 8; off <<= 1) {
            s += __shfl_xor(s, off, 64);
        }
        if (i == 0) {
            const float m = s + be + e_src[src[e]] + e_dst[dst[e]];
            out[e] = 1.0f / (1.0f + expf(-m));
        }
    }
}

extern "C" void kernel_launch(void* const* d_in, const int* in_sizes, int n_in,
                              void* d_out, int out_size, void* d_ws, size_t ws_size,
                              hipStream_t stream) {
    const float* node_feats = (const float*)d_in[0];
    const float* edge_feats = (const float*)d_in[1];
    const int*   src        = (const int*)d_in[2];
    const int*   dst        = (const int*)d_in[3];
    const float* W_src      = (const float*)d_in[4];
    const float* b_src      = (const float*)d_in[5];
    const float* W_dst      = (const float*)d_in[6];
    const float* b_dst      = (const float*)d_in[7];
    const float* W_edge     = (const float*)d_in[8];
    const float* b_edge     = (const float*)d_in[9];

    const int n_nodes = in_sizes[0] / FDIM;
    const int n_edges = in_sizes[2];

    float* e_src = (float*)d_ws;
    float* e_dst = e_src + n_nodes;

    // Kernel 1: 1250 node-groups -> 1250 waves -> 313 blocks of 256.
    {
        int ngroups = (n_nodes + 7) / 8;
        int blocks = (ngroups + 3) / 4;      // 4 waves per 256-thread block
        if (blocks > 2048) blocks = 2048;
        node_gates_kernel<<<blocks, 256, 0, stream>>>(
            node_feats, W_src, W_dst, b_src, b_dst, e_src, e_dst, n_nodes);
    }

    // Kernel 2: 40000 edge-groups over 8192 waves (~4.9 groups each).
    {
        edge_gate_kernel<<<2048, 256, 0, stream>>>(
            edge_feats, src, dst, W_edge, b_edge, e_src, e_dst,
            (float*)d_out, n_edges);
    }
}